// Round 18
// baseline (280.146 us; speedup 1.0000x reference)
//
#include <hip/hip_runtime.h>
#include <hip/hip_bf16.h>
#include <math.h>

// Problem constants (from reference)
#define N_NODES   50000
#define N_EDGES   800000
#define EP        (N_EDGES + N_NODES)   // edges + self loops = 850000
#define IN_CH     128
#define HID       64
#define HEADS     4
#define F1        (HEADS * HID)         // 256
#define OUT_CH    10
#define NUM_GRAPHS 500
#define NEG_SLOPE 0.2f
#define RPAD      132                   // LDS row stride (uints), %32==4: low-conflict
#define NTILES    (N_NODES / 16)        // 3125
#define SCAT_B    ((EP + 255) / 256)    // 3321
#define CAPP      32                    // primary CSR slots/dst (3.2 MB < 4 MB L2/XCD)
#define CAPT      64                    // total capacity (primary+spill); P(deg>64)~1e-20

typedef __attribute__((ext_vector_type(8))) short short8;   // 8 bf16 (4 VGPRs)
typedef __attribute__((ext_vector_type(4))) float floatx4;  // MFMA C/D
typedef __attribute__((ext_vector_type(4))) float fv4;

// bf16 pack/unpack helpers (RNE)
__device__ __forceinline__ unsigned short f2bf(float f) {
    unsigned int u = __float_as_uint(f);
    u += 0x7FFFu + ((u >> 16) & 1u);
    return (unsigned short)(u >> 16);
}
__device__ __forceinline__ unsigned int pack_bf2(float lo, float hi) {
    return (unsigned int)f2bf(lo) | ((unsigned int)f2bf(hi) << 16);
}
__device__ __forceinline__ float bf_lo(unsigned int u) { return __uint_as_float(u << 16); }
__device__ __forceinline__ float bf_hi(unsigned int u) { return __uint_as_float(u & 0xFFFF0000u); }
__device__ __forceinline__ float bf1(unsigned short h) { return __uint_as_float(((unsigned int)h) << 16); }

// ---------------------------------------------------------------------------
// Init: zero cnt + pack W1/W2 into MFMA B-fragment layout (bf16).
// ---------------------------------------------------------------------------
__global__ void init_kernel(int* __restrict__ cnt,
                            const float* __restrict__ W1, unsigned short* __restrict__ W1p,
                            const float* __restrict__ W2, unsigned short* __restrict__ W2p)
{
    const int gid = blockIdx.x * blockDim.x + threadIdx.x;
    if (gid < N_NODES) cnt[gid] = 0;
    if (gid < 4096) {                                        // W1: 16 nt x 4 kt x 64
        const int t = gid >> 8, kt = (gid >> 6) & 3, l = gid & 63;
        const int col = t * 16 + (l & 15);
        unsigned short* o = W1p + (size_t)((t * 4 + kt) * 64 + l) * 8;
        #pragma unroll
        for (int j = 0; j < 8; ++j) {
            const int k = kt * 32 + (l >> 4) * 8 + j;
            o[j] = f2bf(W1[k * F1 + col]);
        }
    } else if (gid < 6144) {                                 // W2: 4 nt x 8 kt x 64
        const int g2 = gid - 4096;
        const int t = g2 >> 9, kt = (g2 >> 6) & 7, l = g2 & 63;
        const int col = t * 16 + (l & 15);
        unsigned short* o = W2p + (size_t)((t * 8 + kt) * 64 + l) * 8;
        #pragma unroll
        for (int j = 0; j < 8; ++j) {
            const int k = kt * 32 + (l >> 4) * 8 + j;
            o[j] = f2bf(W2[k * HID + col]);
        }
    }
}

// ---------------------------------------------------------------------------
// FUSED CSR scatter + GEMM1(+layer-1 logits).
// CSR is two-tier: primary csrA (CAPP=32/dst, 3.2 MB -- fits per-XCD L2 so
// the partial-line RMW traffic stays cached) + rare spill csrB (slots 32..63,
// ~9 nodes expected). All streaming traffic (ei, x loads; H1b stores) uses
// non-temporal hints so it does NOT evict the csrA RMW lines (round-17
// counters: WRITE_SIZE 74.7 MB = every 2B csr store cost a 64B line).
// ---------------------------------------------------------------------------
__global__ __launch_bounds__(256) void scatter_gemm1(
    const int* __restrict__ ei, int* __restrict__ cnt,
    unsigned short* __restrict__ csrA, unsigned short* __restrict__ csrB,
    const float* __restrict__ x, const short* __restrict__ W1p,
    const float* __restrict__ a_src1, const float* __restrict__ a_dst1,
    unsigned short* __restrict__ H1b,
    float* __restrict__ al_s1, float* __restrict__ al_d1)
{
    // ---- scatter slice ----
    const int e = blockIdx.x * 256 + threadIdx.x;
    if (e < EP) {
        int src, dst;
        if (e < N_EDGES) {
            src = __builtin_nontemporal_load(ei + e);
            dst = __builtin_nontemporal_load(ei + N_EDGES + e);
        } else {
            src = dst = e - N_EDGES;
        }
        const int slot = atomicAdd(&cnt[dst], 1);
        if (slot < CAPP)      csrA[dst * CAPP + slot] = (unsigned short)src;
        else if (slot < CAPT) csrB[dst * CAPP + (slot - CAPP)] = (unsigned short)src;
    }
    if (blockIdx.x >= NTILES) return;

    // ---- gemm1 tile ----
    const int m0 = blockIdx.x * 16;
    const int w = threadIdx.x >> 6;
    const int l = threadIdx.x & 63;
    const int q = l >> 4, r = l & 15;
    floatx4 acc[4] = {};
    const float* arow = x + (size_t)(m0 + r) * IN_CH + q * 8;
    #pragma unroll
    for (int kt = 0; kt < 4; ++kt) {
        const fv4 f0 = __builtin_nontemporal_load((const fv4*)(arow + kt * 32));
        const fv4 f1 = __builtin_nontemporal_load((const fv4*)(arow + kt * 32 + 4));
        union { uint4 u; short8 s; } a;
        a.u = make_uint4(pack_bf2(f0.x, f0.y), pack_bf2(f0.z, f0.w),
                         pack_bf2(f1.x, f1.y), pack_bf2(f1.z, f1.w));
        #pragma unroll
        for (int t = 0; t < 4; ++t) {
            const int nt = w * 4 + t;
            const short8 b = *(const short8*)(W1p + (size_t)((nt * 4 + kt) * 64 + l) * 8);
            acc[t] = __builtin_amdgcn_mfma_f32_16x16x32_bf16(a.s, b, acc[t], 0, 0, 0);
        }
    }
    float ls[4] = {0.f, 0.f, 0.f, 0.f}, ld[4] = {0.f, 0.f, 0.f, 0.f};
    #pragma unroll
    for (int t = 0; t < 4; ++t) {
        const int col = (w * 4 + t) * 16 + r;
        const float as = a_src1[col], ad = a_dst1[col];
        #pragma unroll
        for (int reg = 0; reg < 4; ++reg) {
            __builtin_nontemporal_store(f2bf(acc[t][reg]),
                                        H1b + (size_t)(m0 + q * 4 + reg) * F1 + col);
            ls[reg] += acc[t][reg] * as;
            ld[reg] += acc[t][reg] * ad;
        }
    }
    #pragma unroll
    for (int reg = 0; reg < 4; ++reg) {
        #pragma unroll
        for (int off = 8; off > 0; off >>= 1) {     // reduce over 16 cols
            ls[reg] += __shfl_down(ls[reg], off, 16);
            ld[reg] += __shfl_down(ld[reg], off, 16);
        }
    }
    if (r == 0) {
        #pragma unroll
        for (int reg = 0; reg < 4; ++reg) {
            const int n = m0 + q * 4 + reg;
            al_s1[n * HEADS + w] = ls[reg];
            al_d1[n * HEADS + w] = ld[reg];
        }
    }
}

// ---------------------------------------------------------------------------
// FUSED layer-1 aggregation + GEMM2 + layer-2 logits. Two-tier CSR read.
// ---------------------------------------------------------------------------
__global__ __launch_bounds__(256) void agg1_gemm2(
    const int* __restrict__ cnt,
    const unsigned short* __restrict__ csrA, const unsigned short* __restrict__ csrB,
    const float* __restrict__ al_s1, const float* __restrict__ al_d1,
    const uint2* __restrict__ H1b2, const float* __restrict__ b1,
    const short* __restrict__ W2p,
    const float* __restrict__ a_src2, const float* __restrict__ a_dst2,
    unsigned short* __restrict__ H2b,
    float* __restrict__ al_s2, float* __restrict__ al_d2)
{
    const int m0 = blockIdx.x * 16;
    const int w = threadIdx.x >> 6;
    const int l = threadIdx.x & 63;
    __shared__ unsigned int rows[16][RPAD];     // out1 rows: uint u = ch {2u,2u+1}

    // ---- phase A ----
    const int h = l >> 4;                       // this lane's head
    for (int d = 0; d < 4; ++d) {
        const int dst = m0 + w * 4 + d;
        const int n = min(cnt[dst], CAPT);      // <= 64: single chunk
        const float4 ad = *(const float4*)(al_d1 + dst * 4);
        float a0 = 0.f, a1 = 0.f, a2 = 0.f, a3 = 0.f, den = 0.f;
        int s_reg = 0;
        float w0 = 0.f, w1 = 0.f, w2 = 0.f, w3 = 0.f;
        if (l < n) {
            s_reg = (l < CAPP) ? csrA[dst * CAPP + l] : csrB[dst * CAPP + (l - CAPP)];
            const float4 as = *(const float4*)(al_s1 + s_reg * 4);
            float t0 = as.x + ad.x; t0 = t0 > 0.f ? t0 : NEG_SLOPE * t0;
            float t1 = as.y + ad.y; t1 = t1 > 0.f ? t1 : NEG_SLOPE * t1;
            float t2 = as.z + ad.z; t2 = t2 > 0.f ? t2 : NEG_SLOPE * t2;
            float t3 = as.w + ad.w; t3 = t3 > 0.f ? t3 : NEG_SLOPE * t3;
            w0 = __expf(t0); w1 = __expf(t1); w2 = __expf(t2); w3 = __expf(t3);
        }
        const int n4 = (n + 3) & ~3;            // padded lanes carry w=0, s=0
        for (int i = 0; i < n4; i += 4) {
            int   srcj[4];
            float wtj[4];
            #pragma unroll
            for (int j = 0; j < 4; ++j) {
                const int idx = i + j;
                srcj[j] = __shfl(s_reg, idx, 64);
                const float t0 = __shfl(w0, idx, 64);
                const float t1 = __shfl(w1, idx, 64);
                const float t2 = __shfl(w2, idx, 64);
                const float t3 = __shfl(w3, idx, 64);
                wtj[j] = h == 0 ? t0 : (h == 1 ? t1 : (h == 2 ? t2 : t3));
            }
            uint2 u[4];
            #pragma unroll
            for (int j = 0; j < 4; ++j)
                u[j] = H1b2[(size_t)srcj[j] * (F1 / 4) + l];   // 4 in flight
            #pragma unroll
            for (int j = 0; j < 4; ++j) {
                a0 += wtj[j] * bf_lo(u[j].x); a1 += wtj[j] * bf_hi(u[j].x);
                a2 += wtj[j] * bf_lo(u[j].y); a3 += wtj[j] * bf_hi(u[j].y);
                den += wtj[j];
            }
        }
        const float rcp = 1.f / (den + 1e-16f);
        const float4 bb = *(const float4*)(b1 + 4 * l);
        float v0 = a0 * rcp + bb.x; v0 = v0 > 0.f ? v0 : 0.f;
        float v1 = a1 * rcp + bb.y; v1 = v1 > 0.f ? v1 : 0.f;
        float v2 = a2 * rcp + bb.z; v2 = v2 > 0.f ? v2 : 0.f;
        float v3 = a3 * rcp + bb.w; v3 = v3 > 0.f ? v3 : 0.f;
        rows[w * 4 + d][2 * l]     = pack_bf2(v0, v1);
        rows[w * 4 + d][2 * l + 1] = pack_bf2(v2, v3);
    }
    __syncthreads();

    // ---- phase B: H2 = rows @ W2 (wave w owns n-tile w) ----
    const int q = l >> 4, r = l & 15;
    floatx4 acc = {};
    #pragma unroll
    for (int kt = 0; kt < 8; ++kt) {
        union { uint4 u; short8 s; } a;
        a.u = *(const uint4*)&rows[r][kt * 16 + q * 4];   // ds_read_b128
        const short8 b = *(const short8*)(W2p + (size_t)((w * 8 + kt) * 64 + l) * 8);
        acc = __builtin_amdgcn_mfma_f32_16x16x32_bf16(a.s, b, acc, 0, 0, 0);
    }
    const int col = w * 16 + r;
    const float as = a_src2[col], ad2 = a_dst2[col];
    float ls[4], ld[4];
    #pragma unroll
    for (int reg = 0; reg < 4; ++reg) {
        H2b[(size_t)(m0 + q * 4 + reg) * HID + col] = f2bf(acc[reg]);
        ls[reg] = acc[reg] * as;
        ld[reg] = acc[reg] * ad2;
    }
    #pragma unroll
    for (int reg = 0; reg < 4; ++reg) {
        #pragma unroll
        for (int off = 8; off > 0; off >>= 1) {
            ls[reg] += __shfl_down(ls[reg], off, 16);
            ld[reg] += __shfl_down(ld[reg], off, 16);
        }
    }
    __shared__ float Ls[4][16], Ld[4][16];
    if (r == 0) {
        #pragma unroll
        for (int reg = 0; reg < 4; ++reg) {
            Ls[w][q * 4 + reg] = ls[reg];
            Ld[w][q * 4 + reg] = ld[reg];
        }
    }
    __syncthreads();
    if (threadIdx.x < 16) {
        const int row = threadIdx.x;
        al_s2[m0 + row] = Ls[0][row] + Ls[1][row] + Ls[2][row] + Ls[3][row];
        al_d2[m0 + row] = Ld[0][row] + Ld[1][row] + Ld[2][row] + Ld[3][row];
    }
}

// ---------------------------------------------------------------------------
// Layer-2 aggregation (H=1), two-tier CSR, 16-edge groups -> 4 gathers in
// flight (was 2). out2 stored bf16.
// ---------------------------------------------------------------------------
__global__ __launch_bounds__(256) void agg2_csr(
    const int* __restrict__ cnt,
    const unsigned short* __restrict__ csrA, const unsigned short* __restrict__ csrB,
    const float* __restrict__ al_s2, const float* __restrict__ al_d2,
    const uint2* __restrict__ H2b2, uint2* __restrict__ out2b)
{
    const int dst = blockIdx.x * 4 + (threadIdx.x >> 6);
    const int l = threadIdx.x & 63;
    const int qt = l >> 4, j = l & 15;
    const int n = min(cnt[dst], CAPT);
    const float ad = al_d2[dst];
    float a0 = 0.f, a1 = 0.f, a2 = 0.f, a3 = 0.f, den = 0.f;
    int s_reg = 0;
    float w_reg = 0.f;
    if (l < n) {
        s_reg = (l < CAPP) ? csrA[dst * CAPP + l] : csrB[dst * CAPP + (l - CAPP)];
        float t = al_s2[s_reg] + ad;
        t = t > 0.f ? t : NEG_SLOPE * t;
        w_reg = __expf(t);
    }
    const int n16 = (n + 15) & ~15;             // padded: w=0, s=0
    for (int i = 0; i < n16; i += 16) {
        int   srcj[4];
        float wtj[4];
        #pragma unroll
        for (int jj = 0; jj < 4; ++jj) {
            const int idx = i + jj * 4 + qt;    // <= n16-1 <= 63
            srcj[jj] = __shfl(s_reg, idx, 64);
            wtj[jj]  = __shfl(w_reg, idx, 64);
        }
        uint2 u[4];
        #pragma unroll
        for (int jj = 0; jj < 4; ++jj)
            u[jj] = H2b2[(size_t)srcj[jj] * (HID / 4) + j];   // 4 in flight
        #pragma unroll
        for (int jj = 0; jj < 4; ++jj) {
            a0 += wtj[jj] * bf_lo(u[jj].x);
            a1 += wtj[jj] * bf_hi(u[jj].x);
            a2 += wtj[jj] * bf_lo(u[jj].y);
            a3 += wtj[jj] * bf_hi(u[jj].y);
            den += wtj[jj];
        }
    }
    #pragma unroll
    for (int m = 16; m <= 32; m <<= 1) {        // combine 4 edge subsets
        a0 += __shfl_xor(a0, m, 64);
        a1 += __shfl_xor(a1, m, 64);
        a2 += __shfl_xor(a2, m, 64);
        a3 += __shfl_xor(a3, m, 64);
        den += __shfl_xor(den, m, 64);
    }
    if (l < 16) {
        const float rcp = 1.f / (den + 1e-16f);
        out2b[(size_t)dst * (HID / 4) + j] =
            make_uint2(pack_bf2(a0 * rcp, a1 * rcp), pack_bf2(a2 * rcp, a3 * rcp));
    }
}

// ---------------------------------------------------------------------------
// Pool + FC + log_softmax, 4 waves/graph; out2 read as bf16.
// ---------------------------------------------------------------------------
__global__ __launch_bounds__(256) void pool_fc_kernel(
    const unsigned short* __restrict__ out2b, const float* __restrict__ b2,
    const int* __restrict__ batch,
    const float* __restrict__ fc_w, const float* __restrict__ fc_b,
    float* __restrict__ out)
{
    const int g = blockIdx.x;
    const int q = threadIdx.x >> 6, c = threadIdx.x & 63;
    __shared__ int se[2];
    __shared__ float partial[4][HID];
    __shared__ float pl[HID];
    __shared__ float logits[OUT_CH];
    if (threadIdx.x < 2) {
        const int target = g + threadIdx.x;  // lower_bound(batch, target)
        int lo = 0, hi = N_NODES;
        while (lo < hi) { int mid = (lo + hi) >> 1; if (batch[mid] < target) lo = mid + 1; else hi = mid; }
        se[threadIdx.x] = lo;
    }
    __syncthreads();
    const int start = se[0], end = se[1];
    float acc = 0.f;
    for (int n = start + q; n < end; n += 4)
        acc += bf1(out2b[(size_t)n * HID + c]);
    partial[q][c] = acc;
    __syncthreads();
    if (q == 0)
        pl[c] = partial[0][c] + partial[1][c] + partial[2][c] + partial[3][c]
              + (float)(end - start) * b2[c];
    __syncthreads();
    if (threadIdx.x < OUT_CH) {
        float l = fc_b[threadIdx.x];
        #pragma unroll
        for (int k = 0; k < HID; ++k) l += pl[k] * fc_w[k * OUT_CH + threadIdx.x];
        logits[threadIdx.x] = l;
    }
    __syncthreads();
    if (threadIdx.x == 0) {
        float m = logits[0];
        #pragma unroll
        for (int j2 = 1; j2 < OUT_CH; ++j2) m = fmaxf(m, logits[j2]);
        float s = 0.f;
        #pragma unroll
        for (int j2 = 0; j2 < OUT_CH; ++j2) s += __expf(logits[j2] - m);
        const float lse = m + __logf(s);
        #pragma unroll
        for (int j2 = 0; j2 < OUT_CH; ++j2) out[g * OUT_CH + j2] = logits[j2] - lse;
    }
}

// ---------------------------------------------------------------------------
// Workspace ≈ 47 MB. 5 dispatches total.
// ---------------------------------------------------------------------------

extern "C" void kernel_launch(void* const* d_in, const int* in_sizes, int n_in,
                              void* d_out, int out_size, void* d_ws, size_t ws_size,
                              hipStream_t stream)
{
    const float* x      = (const float*)d_in[0];
    const int*   ei     = (const int*)  d_in[1];   // [2, 800000] flat: src row, dst row
    const int*   batch  = (const int*)  d_in[2];
    const float* W1     = (const float*)d_in[3];
    const float* a_src1 = (const float*)d_in[4];
    const float* a_dst1 = (const float*)d_in[5];
    const float* b1     = (const float*)d_in[6];
    const float* W2     = (const float*)d_in[7];
    const float* a_src2 = (const float*)d_in[8];
    const float* a_dst2 = (const float*)d_in[9];
    const float* b2     = (const float*)d_in[10];
    const float* fc_w   = (const float*)d_in[11];
    const float* fc_b   = (const float*)d_in[12];
    float* out = (float*)d_out;

    char* ws = (char*)d_ws;
    size_t off = 0;
    auto alloc_b = [&](size_t bytes) { void* p = (void*)(ws + off); off += (bytes + 15) & ~15ull; return p; };

    unsigned short* H1b  = (unsigned short*)alloc_b((size_t)N_NODES * F1 * 2);     // 25.6 MB
    float* al_s1  = (float*)alloc_b((size_t)N_NODES * HEADS * 4);
    float* al_d1  = (float*)alloc_b((size_t)N_NODES * HEADS * 4);
    unsigned short* H2b  = (unsigned short*)alloc_b((size_t)N_NODES * HID * 2);    // 6.4 MB
    float* al_s2  = (float*)alloc_b((size_t)N_NODES * 4);
    float* al_d2  = (float*)alloc_b((size_t)N_NODES * 4);
    unsigned short* out2b = (unsigned short*)alloc_b((size_t)N_NODES * HID * 2);   // 6.4 MB
    int*   cnt    = (int*)alloc_b((size_t)N_NODES * 4);
    unsigned short* csrA = (unsigned short*)alloc_b((size_t)N_NODES * CAPP * 2);   // 3.2 MB
    unsigned short* csrB = (unsigned short*)alloc_b((size_t)N_NODES * CAPP * 2);   // 3.2 MB
    unsigned short* W1p = (unsigned short*)alloc_b((size_t)IN_CH * F1 * 2);        // 64 KB
    unsigned short* W2p = (unsigned short*)alloc_b((size_t)F1 * HID * 2);          // 32 KB

    // 1) zero cnt + pack weights
    init_kernel<<<(N_NODES + 255) / 256, 256, 0, stream>>>(cnt, W1, W1p, W2, W2p);

    // 2) two-tier CSR scatter || gemm1 (+ layer-1 logits), NT-hinted streams
    scatter_gemm1<<<SCAT_B, 256, 0, stream>>>(ei, cnt, csrA, csrB, x, (const short*)W1p,
                                              a_src1, a_dst1, H1b, al_s1, al_d1);

    // 3) layer-1 aggregation -> (LDS) -> GEMM2 (+ layer-2 logits)
    agg1_gemm2<<<N_NODES / 16, 256, 0, stream>>>(cnt, csrA, csrB, al_s1, al_d1,
                                                 (const uint2*)H1b, b1,
                                                 (const short*)W2p, a_src2, a_dst2,
                                                 H2b, al_s2, al_d2);

    // 4) layer-2 aggregation (writes bf16 out2)
    agg2_csr<<<N_NODES / 4, 256, 0, stream>>>(cnt, csrA, csrB, al_s2, al_d2,
                                              (const uint2*)H2b, (uint2*)out2b);

    // 5) readout (4 waves/graph, bf16 input)
    pool_fc_kernel<<<NUM_GRAPHS, 256, 0, stream>>>(out2b, b2, batch, fc_w, fc_b, out);
}

// Round 19
// 275.922 us; speedup vs baseline: 1.0153x; 1.0153x over previous
//
#include <hip/hip_runtime.h>
#include <hip/hip_bf16.h>
#include <math.h>

// Problem constants (from reference)
#define N_NODES   50000
#define N_EDGES   800000
#define EP        (N_EDGES + N_NODES)   // edges + self loops = 850000
#define IN_CH     128
#define HID       64
#define HEADS     4
#define F1        (HEADS * HID)         // 256
#define OUT_CH    10
#define NUM_GRAPHS 500
#define NEG_SLOPE 0.2f
#define RPAD      132                   // LDS row stride (uints), %32==4: low-conflict
#define NTILES    (N_NODES / 16)        // 3125
#define SCAT_B    ((EP + 255) / 256)    // 3321
#define CAPP      32                    // primary CSR slots/dst (3.2 MB region)
#define CAPT      64                    // total capacity; P(deg>64) ~ 1e-20

typedef __attribute__((ext_vector_type(8))) short short8;   // 8 bf16 (4 VGPRs)
typedef __attribute__((ext_vector_type(4))) float floatx4;  // MFMA C/D
typedef __attribute__((ext_vector_type(4))) float fv4;

// bf16 pack/unpack helpers (RNE)
__device__ __forceinline__ unsigned short f2bf(float f) {
    unsigned int u = __float_as_uint(f);
    u += 0x7FFFu + ((u >> 16) & 1u);
    return (unsigned short)(u >> 16);
}
__device__ __forceinline__ unsigned int pack_bf2(float lo, float hi) {
    return (unsigned int)f2bf(lo) | ((unsigned int)f2bf(hi) << 16);
}
__device__ __forceinline__ float bf_lo(unsigned int u) { return __uint_as_float(u << 16); }
__device__ __forceinline__ float bf_hi(unsigned int u) { return __uint_as_float(u & 0xFFFF0000u); }
__device__ __forceinline__ float bf1(unsigned short h) { return __uint_as_float(((unsigned int)h) << 16); }

// ---------------------------------------------------------------------------
// Init: zero cnt + pack W1/W2 into MFMA B-fragment layout (bf16).
// ---------------------------------------------------------------------------
__global__ void init_kernel(int* __restrict__ cnt,
                            const float* __restrict__ W1, unsigned short* __restrict__ W1p,
                            const float* __restrict__ W2, unsigned short* __restrict__ W2p)
{
    const int gid = blockIdx.x * blockDim.x + threadIdx.x;
    if (gid < N_NODES) cnt[gid] = 0;
    if (gid < 4096) {                                        // W1: 16 nt x 4 kt x 64
        const int t = gid >> 8, kt = (gid >> 6) & 3, l = gid & 63;
        const int col = t * 16 + (l & 15);
        unsigned short* o = W1p + (size_t)((t * 4 + kt) * 64 + l) * 8;
        #pragma unroll
        for (int j = 0; j < 8; ++j) {
            const int k = kt * 32 + (l >> 4) * 8 + j;
            o[j] = f2bf(W1[k * F1 + col]);
        }
    } else if (gid < 6144) {                                 // W2: 4 nt x 8 kt x 64
        const int g2 = gid - 4096;
        const int t = g2 >> 9, kt = (g2 >> 6) & 7, l = g2 & 63;
        const int col = t * 16 + (l & 15);
        unsigned short* o = W2p + (size_t)((t * 8 + kt) * 64 + l) * 8;
        #pragma unroll
        for (int j = 0; j < 8; ++j) {
            const int k = kt * 32 + (l >> 4) * 8 + j;
            o[j] = f2bf(W2[k * HID + col]);
        }
    }
}

// ---------------------------------------------------------------------------
// FUSED CSR scatter + GEMM1(+layer-1 logits).
// Round-18 fix isolated: NT hints ONLY on streaming LOADS (ei, x) so they
// don't allocate in L2 and evict the csr RMW lines; H1b stores are normal
// cached stores (they fill complete 64B lines per block -> merge fine; the
// round-18 NT-store variant cost +22.6 MB of partial-line HBM writes).
// CSR two-tier: primary csrA CAPP=32 (3.2 MB) + rare spill csrB.
// ---------------------------------------------------------------------------
__global__ __launch_bounds__(256) void scatter_gemm1(
    const int* __restrict__ ei, int* __restrict__ cnt,
    unsigned short* __restrict__ csrA, unsigned short* __restrict__ csrB,
    const float* __restrict__ x, const short* __restrict__ W1p,
    const float* __restrict__ a_src1, const float* __restrict__ a_dst1,
    unsigned short* __restrict__ H1b,
    float* __restrict__ al_s1, float* __restrict__ al_d1)
{
    // ---- scatter slice ----
    const int e = blockIdx.x * 256 + threadIdx.x;
    if (e < EP) {
        int src, dst;
        if (e < N_EDGES) {
            src = __builtin_nontemporal_load(ei + e);
            dst = __builtin_nontemporal_load(ei + N_EDGES + e);
        } else {
            src = dst = e - N_EDGES;
        }
        const int slot = atomicAdd(&cnt[dst], 1);
        if (slot < CAPP)      csrA[dst * CAPP + slot] = (unsigned short)src;
        else if (slot < CAPT) csrB[dst * CAPP + (slot - CAPP)] = (unsigned short)src;
    }
    if (blockIdx.x >= NTILES) return;

    // ---- gemm1 tile ----
    const int m0 = blockIdx.x * 16;
    const int w = threadIdx.x >> 6;
    const int l = threadIdx.x & 63;
    const int q = l >> 4, r = l & 15;
    floatx4 acc[4] = {};
    const float* arow = x + (size_t)(m0 + r) * IN_CH + q * 8;
    #pragma unroll
    for (int kt = 0; kt < 4; ++kt) {
        const fv4 f0 = __builtin_nontemporal_load((const fv4*)(arow + kt * 32));
        const fv4 f1 = __builtin_nontemporal_load((const fv4*)(arow + kt * 32 + 4));
        union { uint4 u; short8 s; } a;
        a.u = make_uint4(pack_bf2(f0.x, f0.y), pack_bf2(f0.z, f0.w),
                         pack_bf2(f1.x, f1.y), pack_bf2(f1.z, f1.w));
        #pragma unroll
        for (int t = 0; t < 4; ++t) {
            const int nt = w * 4 + t;
            const short8 b = *(const short8*)(W1p + (size_t)((nt * 4 + kt) * 64 + l) * 8);
            acc[t] = __builtin_amdgcn_mfma_f32_16x16x32_bf16(a.s, b, acc[t], 0, 0, 0);
        }
    }
    float ls[4] = {0.f, 0.f, 0.f, 0.f}, ld[4] = {0.f, 0.f, 0.f, 0.f};
    #pragma unroll
    for (int t = 0; t < 4; ++t) {
        const int col = (w * 4 + t) * 16 + r;
        const float as = a_src1[col], ad = a_dst1[col];
        #pragma unroll
        for (int reg = 0; reg < 4; ++reg) {
            H1b[(size_t)(m0 + q * 4 + reg) * F1 + col] = f2bf(acc[t][reg]);  // cached store
            ls[reg] += acc[t][reg] * as;
            ld[reg] += acc[t][reg] * ad;
        }
    }
    #pragma unroll
    for (int reg = 0; reg < 4; ++reg) {
        #pragma unroll
        for (int off = 8; off > 0; off >>= 1) {     // reduce over 16 cols
            ls[reg] += __shfl_down(ls[reg], off, 16);
            ld[reg] += __shfl_down(ld[reg], off, 16);
        }
    }
    if (r == 0) {
        #pragma unroll
        for (int reg = 0; reg < 4; ++reg) {
            const int n = m0 + q * 4 + reg;
            al_s1[n * HEADS + w] = ls[reg];
            al_d1[n * HEADS + w] = ld[reg];
        }
    }
}

// ---------------------------------------------------------------------------
// FUSED layer-1 aggregation + GEMM2 + layer-2 logits. Two-tier CSR read.
// ---------------------------------------------------------------------------
__global__ __launch_bounds__(256) void agg1_gemm2(
    const int* __restrict__ cnt,
    const unsigned short* __restrict__ csrA, const unsigned short* __restrict__ csrB,
    const float* __restrict__ al_s1, const float* __restrict__ al_d1,
    const uint2* __restrict__ H1b2, const float* __restrict__ b1,
    const short* __restrict__ W2p,
    const float* __restrict__ a_src2, const float* __restrict__ a_dst2,
    unsigned short* __restrict__ H2b,
    float* __restrict__ al_s2, float* __restrict__ al_d2)
{
    const int m0 = blockIdx.x * 16;
    const int w = threadIdx.x >> 6;
    const int l = threadIdx.x & 63;
    __shared__ unsigned int rows[16][RPAD];     // out1 rows: uint u = ch {2u,2u+1}

    // ---- phase A ----
    const int h = l >> 4;                       // this lane's head
    for (int d = 0; d < 4; ++d) {
        const int dst = m0 + w * 4 + d;
        const int n = min(cnt[dst], CAPT);      // <= 64: single chunk
        const float4 ad = *(const float4*)(al_d1 + dst * 4);
        float a0 = 0.f, a1 = 0.f, a2 = 0.f, a3 = 0.f, den = 0.f;
        int s_reg = 0;
        float w0 = 0.f, w1 = 0.f, w2 = 0.f, w3 = 0.f;
        if (l < n) {
            s_reg = (l < CAPP) ? csrA[dst * CAPP + l] : csrB[dst * CAPP + (l - CAPP)];
            const float4 as = *(const float4*)(al_s1 + s_reg * 4);
            float t0 = as.x + ad.x; t0 = t0 > 0.f ? t0 : NEG_SLOPE * t0;
            float t1 = as.y + ad.y; t1 = t1 > 0.f ? t1 : NEG_SLOPE * t1;
            float t2 = as.z + ad.z; t2 = t2 > 0.f ? t2 : NEG_SLOPE * t2;
            float t3 = as.w + ad.w; t3 = t3 > 0.f ? t3 : NEG_SLOPE * t3;
            w0 = __expf(t0); w1 = __expf(t1); w2 = __expf(t2); w3 = __expf(t3);
        }
        const int n4 = (n + 3) & ~3;            // padded lanes carry w=0, s=0
        for (int i = 0; i < n4; i += 4) {
            int   srcj[4];
            float wtj[4];
            #pragma unroll
            for (int j = 0; j < 4; ++j) {
                const int idx = i + j;
                srcj[j] = __shfl(s_reg, idx, 64);
                const float t0 = __shfl(w0, idx, 64);
                const float t1 = __shfl(w1, idx, 64);
                const float t2 = __shfl(w2, idx, 64);
                const float t3 = __shfl(w3, idx, 64);
                wtj[j] = h == 0 ? t0 : (h == 1 ? t1 : (h == 2 ? t2 : t3));
            }
            uint2 u[4];
            #pragma unroll
            for (int j = 0; j < 4; ++j)
                u[j] = H1b2[(size_t)srcj[j] * (F1 / 4) + l];   // 4 in flight
            #pragma unroll
            for (int j = 0; j < 4; ++j) {
                a0 += wtj[j] * bf_lo(u[j].x); a1 += wtj[j] * bf_hi(u[j].x);
                a2 += wtj[j] * bf_lo(u[j].y); a3 += wtj[j] * bf_hi(u[j].y);
                den += wtj[j];
            }
        }
        const float rcp = 1.f / (den + 1e-16f);
        const float4 bb = *(const float4*)(b1 + 4 * l);
        float v0 = a0 * rcp + bb.x; v0 = v0 > 0.f ? v0 : 0.f;
        float v1 = a1 * rcp + bb.y; v1 = v1 > 0.f ? v1 : 0.f;
        float v2 = a2 * rcp + bb.z; v2 = v2 > 0.f ? v2 : 0.f;
        float v3 = a3 * rcp + bb.w; v3 = v3 > 0.f ? v3 : 0.f;
        rows[w * 4 + d][2 * l]     = pack_bf2(v0, v1);
        rows[w * 4 + d][2 * l + 1] = pack_bf2(v2, v3);
    }
    __syncthreads();

    // ---- phase B: H2 = rows @ W2 (wave w owns n-tile w) ----
    const int q = l >> 4, r = l & 15;
    floatx4 acc = {};
    #pragma unroll
    for (int kt = 0; kt < 8; ++kt) {
        union { uint4 u; short8 s; } a;
        a.u = *(const uint4*)&rows[r][kt * 16 + q * 4];   // ds_read_b128
        const short8 b = *(const short8*)(W2p + (size_t)((w * 8 + kt) * 64 + l) * 8);
        acc = __builtin_amdgcn_mfma_f32_16x16x32_bf16(a.s, b, acc, 0, 0, 0);
    }
    const int col = w * 16 + r;
    const float as = a_src2[col], ad2 = a_dst2[col];
    float ls[4], ld[4];
    #pragma unroll
    for (int reg = 0; reg < 4; ++reg) {
        H2b[(size_t)(m0 + q * 4 + reg) * HID + col] = f2bf(acc[reg]);
        ls[reg] = acc[reg] * as;
        ld[reg] = acc[reg] * ad2;
    }
    #pragma unroll
    for (int reg = 0; reg < 4; ++reg) {
        #pragma unroll
        for (int off = 8; off > 0; off >>= 1) {
            ls[reg] += __shfl_down(ls[reg], off, 16);
            ld[reg] += __shfl_down(ld[reg], off, 16);
        }
    }
    __shared__ float Ls[4][16], Ld[4][16];
    if (r == 0) {
        #pragma unroll
        for (int reg = 0; reg < 4; ++reg) {
            Ls[w][q * 4 + reg] = ls[reg];
            Ld[w][q * 4 + reg] = ld[reg];
        }
    }
    __syncthreads();
    if (threadIdx.x < 16) {
        const int row = threadIdx.x;
        al_s2[m0 + row] = Ls[0][row] + Ls[1][row] + Ls[2][row] + Ls[3][row];
        al_d2[m0 + row] = Ld[0][row] + Ld[1][row] + Ld[2][row] + Ld[3][row];
    }
}

// ---------------------------------------------------------------------------
// Layer-2 aggregation (H=1), two-tier CSR, 16-edge groups -> 4 gathers in
// flight. out2 stored bf16.
// ---------------------------------------------------------------------------
__global__ __launch_bounds__(256) void agg2_csr(
    const int* __restrict__ cnt,
    const unsigned short* __restrict__ csrA, const unsigned short* __restrict__ csrB,
    const float* __restrict__ al_s2, const float* __restrict__ al_d2,
    const uint2* __restrict__ H2b2, uint2* __restrict__ out2b)
{
    const int dst = blockIdx.x * 4 + (threadIdx.x >> 6);
    const int l = threadIdx.x & 63;
    const int qt = l >> 4, j = l & 15;
    const int n = min(cnt[dst], CAPT);
    const float ad = al_d2[dst];
    float a0 = 0.f, a1 = 0.f, a2 = 0.f, a3 = 0.f, den = 0.f;
    int s_reg = 0;
    float w_reg = 0.f;
    if (l < n) {
        s_reg = (l < CAPP) ? csrA[dst * CAPP + l] : csrB[dst * CAPP + (l - CAPP)];
        float t = al_s2[s_reg] + ad;
        t = t > 0.f ? t : NEG_SLOPE * t;
        w_reg = __expf(t);
    }
    const int n16 = (n + 15) & ~15;             // padded: w=0, s=0
    for (int i = 0; i < n16; i += 16) {
        int   srcj[4];
        float wtj[4];
        #pragma unroll
        for (int jj = 0; jj < 4; ++jj) {
            const int idx = i + jj * 4 + qt;    // <= 63
            srcj[jj] = __shfl(s_reg, idx, 64);
            wtj[jj]  = __shfl(w_reg, idx, 64);
        }
        uint2 u[4];
        #pragma unroll
        for (int jj = 0; jj < 4; ++jj)
            u[jj] = H2b2[(size_t)srcj[jj] * (HID / 4) + j];   // 4 in flight
        #pragma unroll
        for (int jj = 0; jj < 4; ++jj) {
            a0 += wtj[jj] * bf_lo(u[jj].x);
            a1 += wtj[jj] * bf_hi(u[jj].x);
            a2 += wtj[jj] * bf_lo(u[jj].y);
            a3 += wtj[jj] * bf_hi(u[jj].y);
            den += wtj[jj];
        }
    }
    #pragma unroll
    for (int m = 16; m <= 32; m <<= 1) {        // combine 4 edge subsets
        a0 += __shfl_xor(a0, m, 64);
        a1 += __shfl_xor(a1, m, 64);
        a2 += __shfl_xor(a2, m, 64);
        a3 += __shfl_xor(a3, m, 64);
        den += __shfl_xor(den, m, 64);
    }
    if (l < 16) {
        const float rcp = 1.f / (den + 1e-16f);
        out2b[(size_t)dst * (HID / 4) + j] =
            make_uint2(pack_bf2(a0 * rcp, a1 * rcp), pack_bf2(a2 * rcp, a3 * rcp));
    }
}

// ---------------------------------------------------------------------------
// Pool + FC + log_softmax, 4 waves/graph; out2 read as bf16.
// ---------------------------------------------------------------------------
__global__ __launch_bounds__(256) void pool_fc_kernel(
    const unsigned short* __restrict__ out2b, const float* __restrict__ b2,
    const int* __restrict__ batch,
    const float* __restrict__ fc_w, const float* __restrict__ fc_b,
    float* __restrict__ out)
{
    const int g = blockIdx.x;
    const int q = threadIdx.x >> 6, c = threadIdx.x & 63;
    __shared__ int se[2];
    __shared__ float partial[4][HID];
    __shared__ float pl[HID];
    __shared__ float logits[OUT_CH];
    if (threadIdx.x < 2) {
        const int target = g + threadIdx.x;  // lower_bound(batch, target)
        int lo = 0, hi = N_NODES;
        while (lo < hi) { int mid = (lo + hi) >> 1; if (batch[mid] < target) lo = mid + 1; else hi = mid; }
        se[threadIdx.x] = lo;
    }
    __syncthreads();
    const int start = se[0], end = se[1];
    float acc = 0.f;
    for (int n = start + q; n < end; n += 4)
        acc += bf1(out2b[(size_t)n * HID + c]);
    partial[q][c] = acc;
    __syncthreads();
    if (q == 0)
        pl[c] = partial[0][c] + partial[1][c] + partial[2][c] + partial[3][c]
              + (float)(end - start) * b2[c];
    __syncthreads();
    if (threadIdx.x < OUT_CH) {
        float l = fc_b[threadIdx.x];
        #pragma unroll
        for (int k = 0; k < HID; ++k) l += pl[k] * fc_w[k * OUT_CH + threadIdx.x];
        logits[threadIdx.x] = l;
    }
    __syncthreads();
    if (threadIdx.x == 0) {
        float m = logits[0];
        #pragma unroll
        for (int j2 = 1; j2 < OUT_CH; ++j2) m = fmaxf(m, logits[j2]);
        float s = 0.f;
        #pragma unroll
        for (int j2 = 0; j2 < OUT_CH; ++j2) s += __expf(logits[j2] - m);
        const float lse = m + __logf(s);
        #pragma unroll
        for (int j2 = 0; j2 < OUT_CH; ++j2) out[g * OUT_CH + j2] = logits[j2] - lse;
    }
}

// ---------------------------------------------------------------------------
// Workspace ≈ 47 MB. 5 dispatches total.
// ---------------------------------------------------------------------------

extern "C" void kernel_launch(void* const* d_in, const int* in_sizes, int n_in,
                              void* d_out, int out_size, void* d_ws, size_t ws_size,
                              hipStream_t stream)
{
    const float* x      = (const float*)d_in[0];
    const int*   ei     = (const int*)  d_in[1];   // [2, 800000] flat: src row, dst row
    const int*   batch  = (const int*)  d_in[2];
    const float* W1     = (const float*)d_in[3];
    const float* a_src1 = (const float*)d_in[4];
    const float* a_dst1 = (const float*)d_in[5];
    const float* b1     = (const float*)d_in[6];
    const float* W2     = (const float*)d_in[7];
    const float* a_src2 = (const float*)d_in[8];
    const float* a_dst2 = (const float*)d_in[9];
    const float* b2     = (const float*)d_in[10];
    const float* fc_w   = (const float*)d_in[11];
    const float* fc_b   = (const float*)d_in[12];
    float* out = (float*)d_out;

    char* ws = (char*)d_ws;
    size_t off = 0;
    auto alloc_b = [&](size_t bytes) { void* p = (void*)(ws + off); off += (bytes + 15) & ~15ull; return p; };

    unsigned short* H1b  = (unsigned short*)alloc_b((size_t)N_NODES * F1 * 2);     // 25.6 MB
    float* al_s1  = (float*)alloc_b((size_t)N_NODES * HEADS * 4);
    float* al_d1  = (float*)alloc_b((size_t)N_NODES * HEADS * 4);
    unsigned short* H2b  = (unsigned short*)alloc_b((size_t)N_NODES * HID * 2);    // 6.4 MB
    float* al_s2  = (float*)alloc_b((size_t)N_NODES * 4);
    float* al_d2  = (float*)alloc_b((size_t)N_NODES * 4);
    unsigned short* out2b = (unsigned short*)alloc_b((size_t)N_NODES * HID * 2);   // 6.4 MB
    int*   cnt    = (int*)alloc_b((size_t)N_NODES * 4);
    unsigned short* csrA = (unsigned short*)alloc_b((size_t)N_NODES * CAPP * 2);   // 3.2 MB
    unsigned short* csrB = (unsigned short*)alloc_b((size_t)N_NODES * CAPP * 2);   // 3.2 MB
    unsigned short* W1p = (unsigned short*)alloc_b((size_t)IN_CH * F1 * 2);        // 64 KB
    unsigned short* W2p = (unsigned short*)alloc_b((size_t)F1 * HID * 2);          // 32 KB

    // 1) zero cnt + pack weights
    init_kernel<<<(N_NODES + 255) / 256, 256, 0, stream>>>(cnt, W1, W1p, W2, W2p);

    // 2) two-tier CSR scatter || gemm1 (NT loads only; cached H1b stores)
    scatter_gemm1<<<SCAT_B, 256, 0, stream>>>(ei, cnt, csrA, csrB, x, (const short*)W1p,
                                              a_src1, a_dst1, H1b, al_s1, al_d1);

    // 3) layer-1 aggregation -> (LDS) -> GEMM2 (+ layer-2 logits)
    agg1_gemm2<<<N_NODES / 16, 256, 0, stream>>>(cnt, csrA, csrB, al_s1, al_d1,
                                                 (const uint2*)H1b, b1,
                                                 (const short*)W2p, a_src2, a_dst2,
                                                 H2b, al_s2, al_d2);

    // 4) layer-2 aggregation (writes bf16 out2)
    agg2_csr<<<N_NODES / 4, 256, 0, stream>>>(cnt, csrA, csrB, al_s2, al_d2,
                                              (const uint2*)H2b, (uint2*)out2b);

    // 5) readout (4 waves/graph, bf16 input)
    pool_fc_kernel<<<NUM_GRAPHS, 256, 0, stream>>>(out2b, b2, batch, fc_w, fc_b, out);
}

// Round 20
// 248.252 us; speedup vs baseline: 1.1285x; 1.1115x over previous
//
#include <hip/hip_runtime.h>
#include <hip/hip_bf16.h>
#include <math.h>

// Problem constants (from reference)
#define N_NODES   50000
#define N_EDGES   800000
#define EP        (N_EDGES + N_NODES)   // edges + self loops = 850000
#define IN_CH     128
#define HID       64
#define HEADS     4
#define F1        (HEADS * HID)         // 256
#define OUT_CH    10
#define NUM_GRAPHS 500
#define NEG_SLOPE 0.2f
#define RPAD      132                   // LDS row stride (uints), %32==4: low-conflict
#define NTILES    (N_NODES / 16)        // 3125
#define SCAT_B    ((EP + 255) / 256)    // 3321
#define CAP       64                    // fixed CSR slots/dst; deg ~ Poisson(16)+1,
                                        // max over 50K nodes ~45 -> P(overflow) ~ 1e-15

typedef __attribute__((ext_vector_type(8))) short short8;   // 8 bf16 (4 VGPRs)
typedef __attribute__((ext_vector_type(4))) float floatx4;  // MFMA C/D

// bf16 pack/unpack helpers (RNE)
__device__ __forceinline__ unsigned short f2bf(float f) {
    unsigned int u = __float_as_uint(f);
    u += 0x7FFFu + ((u >> 16) & 1u);
    return (unsigned short)(u >> 16);
}
__device__ __forceinline__ unsigned int pack_bf2(float lo, float hi) {
    return (unsigned int)f2bf(lo) | ((unsigned int)f2bf(hi) << 16);
}
__device__ __forceinline__ float bf_lo(unsigned int u) { return __uint_as_float(u << 16); }
__device__ __forceinline__ float bf_hi(unsigned int u) { return __uint_as_float(u & 0xFFFF0000u); }
__device__ __forceinline__ float bf1(unsigned short h) { return __uint_as_float(((unsigned int)h) << 16); }

// ---------------------------------------------------------------------------
// Init: zero cnt + pack W1/W2 into MFMA B-fragment layout (bf16).
// ---------------------------------------------------------------------------
__global__ void init_kernel(int* __restrict__ cnt,
                            const float* __restrict__ W1, unsigned short* __restrict__ W1p,
                            const float* __restrict__ W2, unsigned short* __restrict__ W2p)
{
    const int gid = blockIdx.x * blockDim.x + threadIdx.x;
    if (gid < N_NODES) cnt[gid] = 0;
    if (gid < 4096) {                                        // W1: 16 nt x 4 kt x 64
        const int t = gid >> 8, kt = (gid >> 6) & 3, l = gid & 63;
        const int col = t * 16 + (l & 15);
        unsigned short* o = W1p + (size_t)((t * 4 + kt) * 64 + l) * 8;
        #pragma unroll
        for (int j = 0; j < 8; ++j) {
            const int k = kt * 32 + (l >> 4) * 8 + j;
            o[j] = f2bf(W1[k * F1 + col]);
        }
    } else if (gid < 6144) {                                 // W2: 4 nt x 8 kt x 64
        const int g2 = gid - 4096;
        const int t = g2 >> 9, kt = (g2 >> 6) & 7, l = g2 & 63;
        const int col = t * 16 + (l & 15);
        unsigned short* o = W2p + (size_t)((t * 8 + kt) * 64 + l) * 8;
        #pragma unroll
        for (int j = 0; j < 8; ++j) {
            const int k = kt * 32 + (l >> 4) * 8 + j;
            o[j] = f2bf(W2[k * HID + col]);
        }
    }
}

// ---------------------------------------------------------------------------
// FUSED fixed-cap CSR scatter + GEMM1(+layer-1 logits). Round-17 form (the
// measured best). NT/two-tier variants (r18/r19) both INCREASED writeback:
// the ~75 MB scattered-store writeback is structural (lines dirtied from all
// 8 XCDs bounce across non-coherent L2s) — do not re-attempt with hints.
// ---------------------------------------------------------------------------
__global__ __launch_bounds__(256) void scatter_gemm1(
    const int* __restrict__ ei, int* __restrict__ cnt,
    unsigned short* __restrict__ csr,
    const float* __restrict__ x, const short* __restrict__ W1p,
    const float* __restrict__ a_src1, const float* __restrict__ a_dst1,
    unsigned short* __restrict__ H1b,
    float* __restrict__ al_s1, float* __restrict__ al_d1)
{
    // ---- scatter slice ----
    const int e = blockIdx.x * 256 + threadIdx.x;
    if (e < EP) {
        int src, dst;
        if (e < N_EDGES) { src = ei[e]; dst = ei[N_EDGES + e]; }
        else             { src = dst = e - N_EDGES; }
        const int slot = atomicAdd(&cnt[dst], 1);
        if (slot < CAP) csr[dst * CAP + slot] = (unsigned short)src;
    }
    if (blockIdx.x >= NTILES) return;

    // ---- gemm1 tile ----
    const int m0 = blockIdx.x * 16;
    const int w = threadIdx.x >> 6;
    const int l = threadIdx.x & 63;
    const int q = l >> 4, r = l & 15;
    floatx4 acc[4] = {};
    const float* arow = x + (size_t)(m0 + r) * IN_CH + q * 8;
    #pragma unroll
    for (int kt = 0; kt < 4; ++kt) {
        const float4 f0 = *(const float4*)(arow + kt * 32);
        const float4 f1 = *(const float4*)(arow + kt * 32 + 4);
        union { uint4 u; short8 s; } a;
        a.u = make_uint4(pack_bf2(f0.x, f0.y), pack_bf2(f0.z, f0.w),
                         pack_bf2(f1.x, f1.y), pack_bf2(f1.z, f1.w));
        #pragma unroll
        for (int t = 0; t < 4; ++t) {
            const int nt = w * 4 + t;
            const short8 b = *(const short8*)(W1p + (size_t)((nt * 4 + kt) * 64 + l) * 8);
            acc[t] = __builtin_amdgcn_mfma_f32_16x16x32_bf16(a.s, b, acc[t], 0, 0, 0);
        }
    }
    float ls[4] = {0.f, 0.f, 0.f, 0.f}, ld[4] = {0.f, 0.f, 0.f, 0.f};
    #pragma unroll
    for (int t = 0; t < 4; ++t) {
        const int col = (w * 4 + t) * 16 + r;
        const float as = a_src1[col], ad = a_dst1[col];
        #pragma unroll
        for (int reg = 0; reg < 4; ++reg) {
            H1b[(size_t)(m0 + q * 4 + reg) * F1 + col] = f2bf(acc[t][reg]);
            ls[reg] += acc[t][reg] * as;
            ld[reg] += acc[t][reg] * ad;
        }
    }
    #pragma unroll
    for (int reg = 0; reg < 4; ++reg) {
        #pragma unroll
        for (int off = 8; off > 0; off >>= 1) {     // reduce over 16 cols
            ls[reg] += __shfl_down(ls[reg], off, 16);
            ld[reg] += __shfl_down(ld[reg], off, 16);
        }
    }
    if (r == 0) {
        #pragma unroll
        for (int reg = 0; reg < 4; ++reg) {
            const int n = m0 + q * 4 + reg;
            al_s1[n * HEADS + w] = ls[reg];
            al_d1[n * HEADS + w] = ld[reg];
        }
    }
}

// ---------------------------------------------------------------------------
// FUSED layer-1 aggregation + GEMM2 + layer-2 logits. Fixed-cap CSR:
// beg = dst*CAP, end = beg + min(cnt[dst], CAP).
// ---------------------------------------------------------------------------
__global__ __launch_bounds__(256) void agg1_gemm2(
    const int* __restrict__ cnt, const unsigned short* __restrict__ csr,
    const float* __restrict__ al_s1, const float* __restrict__ al_d1,
    const uint2* __restrict__ H1b2, const float* __restrict__ b1,
    const short* __restrict__ W2p,
    const float* __restrict__ a_src2, const float* __restrict__ a_dst2,
    unsigned short* __restrict__ H2b,
    float* __restrict__ al_s2, float* __restrict__ al_d2)
{
    const int m0 = blockIdx.x * 16;
    const int w = threadIdx.x >> 6;
    const int l = threadIdx.x & 63;
    __shared__ unsigned int rows[16][RPAD];     // out1 rows: uint u = ch {2u,2u+1}

    // ---- phase A ----
    const int h = l >> 4;                       // this lane's head
    for (int d = 0; d < 4; ++d) {
        const int dst = m0 + w * 4 + d;
        const int n = min(cnt[dst], CAP);       // <= 64: single chunk
        const float4 ad = *(const float4*)(al_d1 + dst * 4);
        float a0 = 0.f, a1 = 0.f, a2 = 0.f, a3 = 0.f, den = 0.f;
        int s_reg = 0;
        float w0 = 0.f, w1 = 0.f, w2 = 0.f, w3 = 0.f;
        if (l < n) {
            s_reg = csr[dst * CAP + l];
            const float4 as = *(const float4*)(al_s1 + s_reg * 4);
            float t0 = as.x + ad.x; t0 = t0 > 0.f ? t0 : NEG_SLOPE * t0;
            float t1 = as.y + ad.y; t1 = t1 > 0.f ? t1 : NEG_SLOPE * t1;
            float t2 = as.z + ad.z; t2 = t2 > 0.f ? t2 : NEG_SLOPE * t2;
            float t3 = as.w + ad.w; t3 = t3 > 0.f ? t3 : NEG_SLOPE * t3;
            w0 = __expf(t0); w1 = __expf(t1); w2 = __expf(t2); w3 = __expf(t3);
        }
        const int n4 = (n + 3) & ~3;            // padded lanes carry w=0, s=0
        for (int i = 0; i < n4; i += 4) {
            int   srcj[4];
            float wtj[4];
            #pragma unroll
            for (int j = 0; j < 4; ++j) {
                const int idx = i + j;
                srcj[j] = __shfl(s_reg, idx, 64);
                const float t0 = __shfl(w0, idx, 64);
                const float t1 = __shfl(w1, idx, 64);
                const float t2 = __shfl(w2, idx, 64);
                const float t3 = __shfl(w3, idx, 64);
                wtj[j] = h == 0 ? t0 : (h == 1 ? t1 : (h == 2 ? t2 : t3));
            }
            uint2 u[4];
            #pragma unroll
            for (int j = 0; j < 4; ++j)
                u[j] = H1b2[(size_t)srcj[j] * (F1 / 4) + l];   // 4 in flight
            #pragma unroll
            for (int j = 0; j < 4; ++j) {
                a0 += wtj[j] * bf_lo(u[j].x); a1 += wtj[j] * bf_hi(u[j].x);
                a2 += wtj[j] * bf_lo(u[j].y); a3 += wtj[j] * bf_hi(u[j].y);
                den += wtj[j];
            }
        }
        const float rcp = 1.f / (den + 1e-16f);
        const float4 bb = *(const float4*)(b1 + 4 * l);
        float v0 = a0 * rcp + bb.x; v0 = v0 > 0.f ? v0 : 0.f;
        float v1 = a1 * rcp + bb.y; v1 = v1 > 0.f ? v1 : 0.f;
        float v2 = a2 * rcp + bb.z; v2 = v2 > 0.f ? v2 : 0.f;
        float v3 = a3 * rcp + bb.w; v3 = v3 > 0.f ? v3 : 0.f;
        rows[w * 4 + d][2 * l]     = pack_bf2(v0, v1);
        rows[w * 4 + d][2 * l + 1] = pack_bf2(v2, v3);
    }
    __syncthreads();

    // ---- phase B: H2 = rows @ W2 (wave w owns n-tile w) ----
    const int q = l >> 4, r = l & 15;
    floatx4 acc = {};
    #pragma unroll
    for (int kt = 0; kt < 8; ++kt) {
        union { uint4 u; short8 s; } a;
        a.u = *(const uint4*)&rows[r][kt * 16 + q * 4];   // ds_read_b128
        const short8 b = *(const short8*)(W2p + (size_t)((w * 8 + kt) * 64 + l) * 8);
        acc = __builtin_amdgcn_mfma_f32_16x16x32_bf16(a.s, b, acc, 0, 0, 0);
    }
    const int col = w * 16 + r;
    const float as = a_src2[col], ad2 = a_dst2[col];
    float ls[4], ld[4];
    #pragma unroll
    for (int reg = 0; reg < 4; ++reg) {
        H2b[(size_t)(m0 + q * 4 + reg) * HID + col] = f2bf(acc[reg]);
        ls[reg] = acc[reg] * as;
        ld[reg] = acc[reg] * ad2;
    }
    #pragma unroll
    for (int reg = 0; reg < 4; ++reg) {
        #pragma unroll
        for (int off = 8; off > 0; off >>= 1) {
            ls[reg] += __shfl_down(ls[reg], off, 16);
            ld[reg] += __shfl_down(ld[reg], off, 16);
        }
    }
    __shared__ float Ls[4][16], Ld[4][16];
    if (r == 0) {
        #pragma unroll
        for (int reg = 0; reg < 4; ++reg) {
            Ls[w][q * 4 + reg] = ls[reg];
            Ld[w][q * 4 + reg] = ld[reg];
        }
    }
    __syncthreads();
    if (threadIdx.x < 16) {
        const int row = threadIdx.x;
        al_s2[m0 + row] = Ls[0][row] + Ls[1][row] + Ls[2][row] + Ls[3][row];
        al_d2[m0 + row] = Ld[0][row] + Ld[1][row] + Ld[2][row] + Ld[3][row];
    }
}

// ---------------------------------------------------------------------------
// Layer-2 aggregation, fixed-cap CSR (H=1). out2 stored bf16.
// ---------------------------------------------------------------------------
__global__ __launch_bounds__(256) void agg2_csr(
    const int* __restrict__ cnt, const unsigned short* __restrict__ csr,
    const float* __restrict__ al_s2, const float* __restrict__ al_d2,
    const uint2* __restrict__ H2b2, uint2* __restrict__ out2b)
{
    const int dst = blockIdx.x * 4 + (threadIdx.x >> 6);
    const int l = threadIdx.x & 63;
    const int qt = l >> 4, j = l & 15;
    const int n = min(cnt[dst], CAP);
    const float ad = al_d2[dst];
    float a0 = 0.f, a1 = 0.f, a2 = 0.f, a3 = 0.f, den = 0.f;
    int s_reg = 0;
    float w_reg = 0.f;
    if (l < n) {
        s_reg = csr[dst * CAP + l];
        float t = al_s2[s_reg] + ad;
        t = t > 0.f ? t : NEG_SLOPE * t;
        w_reg = __expf(t);
    }
    const int n8 = (n + 7) & ~7;                // padded: w=0, s=0
    for (int i = 0; i < n8; i += 8) {
        const int e0 = i + qt, e1 = i + 4 + qt;
        const int   src0 = __shfl(s_reg, e0, 64), src1 = __shfl(s_reg, e1, 64);
        const float wt0  = __shfl(w_reg, e0, 64), wt1  = __shfl(w_reg, e1, 64);
        const uint2 u0 = H2b2[(size_t)src0 * (HID / 4) + j];
        const uint2 u1 = H2b2[(size_t)src1 * (HID / 4) + j];
        a0 += wt0 * bf_lo(u0.x) + wt1 * bf_lo(u1.x);
        a1 += wt0 * bf_hi(u0.x) + wt1 * bf_hi(u1.x);
        a2 += wt0 * bf_lo(u0.y) + wt1 * bf_lo(u1.y);
        a3 += wt0 * bf_hi(u0.y) + wt1 * bf_hi(u1.y);
        den += wt0 + wt1;
    }
    #pragma unroll
    for (int m = 16; m <= 32; m <<= 1) {        // combine 4 edge subsets
        a0 += __shfl_xor(a0, m, 64);
        a1 += __shfl_xor(a1, m, 64);
        a2 += __shfl_xor(a2, m, 64);
        a3 += __shfl_xor(a3, m, 64);
        den += __shfl_xor(den, m, 64);
    }
    if (l < 16) {
        const float rcp = 1.f / (den + 1e-16f);
        out2b[(size_t)dst * (HID / 4) + j] =
            make_uint2(pack_bf2(a0 * rcp, a1 * rcp), pack_bf2(a2 * rcp, a3 * rcp));
    }
}

// ---------------------------------------------------------------------------
// Pool + FC + log_softmax, 4 waves/graph; out2 read as bf16.
// ---------------------------------------------------------------------------
__global__ __launch_bounds__(256) void pool_fc_kernel(
    const unsigned short* __restrict__ out2b, const float* __restrict__ b2,
    const int* __restrict__ batch,
    const float* __restrict__ fc_w, const float* __restrict__ fc_b,
    float* __restrict__ out)
{
    const int g = blockIdx.x;
    const int q = threadIdx.x >> 6, c = threadIdx.x & 63;
    __shared__ int se[2];
    __shared__ float partial[4][HID];
    __shared__ float pl[HID];
    __shared__ float logits[OUT_CH];
    if (threadIdx.x < 2) {
        const int target = g + threadIdx.x;  // lower_bound(batch, target)
        int lo = 0, hi = N_NODES;
        while (lo < hi) { int mid = (lo + hi) >> 1; if (batch[mid] < target) lo = mid + 1; else hi = mid; }
        se[threadIdx.x] = lo;
    }
    __syncthreads();
    const int start = se[0], end = se[1];
    float acc = 0.f;
    for (int n = start + q; n < end; n += 4)
        acc += bf1(out2b[(size_t)n * HID + c]);
    partial[q][c] = acc;
    __syncthreads();
    if (q == 0)
        pl[c] = partial[0][c] + partial[1][c] + partial[2][c] + partial[3][c]
              + (float)(end - start) * b2[c];
    __syncthreads();
    if (threadIdx.x < OUT_CH) {
        float l = fc_b[threadIdx.x];
        #pragma unroll
        for (int k = 0; k < HID; ++k) l += pl[k] * fc_w[k * OUT_CH + threadIdx.x];
        logits[threadIdx.x] = l;
    }
    __syncthreads();
    if (threadIdx.x == 0) {
        float m = logits[0];
        #pragma unroll
        for (int j2 = 1; j2 < OUT_CH; ++j2) m = fmaxf(m, logits[j2]);
        float s = 0.f;
        #pragma unroll
        for (int j2 = 0; j2 < OUT_CH; ++j2) s += __expf(logits[j2] - m);
        const float lse = m + __logf(s);
        #pragma unroll
        for (int j2 = 0; j2 < OUT_CH; ++j2) out[g * OUT_CH + j2] = logits[j2] - lse;
    }
}

// ---------------------------------------------------------------------------
// Workspace ≈ 47 MB. 5 dispatches total. (Round-17 config — measured best.)
// ---------------------------------------------------------------------------

extern "C" void kernel_launch(void* const* d_in, const int* in_sizes, int n_in,
                              void* d_out, int out_size, void* d_ws, size_t ws_size,
                              hipStream_t stream)
{
    const float* x      = (const float*)d_in[0];
    const int*   ei     = (const int*)  d_in[1];   // [2, 800000] flat: src row, dst row
    const int*   batch  = (const int*)  d_in[2];
    const float* W1     = (const float*)d_in[3];
    const float* a_src1 = (const float*)d_in[4];
    const float* a_dst1 = (const float*)d_in[5];
    const float* b1     = (const float*)d_in[6];
    const float* W2     = (const float*)d_in[7];
    const float* a_src2 = (const float*)d_in[8];
    const float* a_dst2 = (const float*)d_in[9];
    const float* b2     = (const float*)d_in[10];
    const float* fc_w   = (const float*)d_in[11];
    const float* fc_b   = (const float*)d_in[12];
    float* out = (float*)d_out;

    char* ws = (char*)d_ws;
    size_t off = 0;
    auto alloc_b = [&](size_t bytes) { void* p = (void*)(ws + off); off += (bytes + 15) & ~15ull; return p; };

    unsigned short* H1b  = (unsigned short*)alloc_b((size_t)N_NODES * F1 * 2);     // 25.6 MB
    float* al_s1  = (float*)alloc_b((size_t)N_NODES * HEADS * 4);
    float* al_d1  = (float*)alloc_b((size_t)N_NODES * HEADS * 4);
    unsigned short* H2b  = (unsigned short*)alloc_b((size_t)N_NODES * HID * 2);    // 6.4 MB
    float* al_s2  = (float*)alloc_b((size_t)N_NODES * 4);
    float* al_d2  = (float*)alloc_b((size_t)N_NODES * 4);
    unsigned short* out2b = (unsigned short*)alloc_b((size_t)N_NODES * HID * 2);   // 6.4 MB
    int*   cnt    = (int*)alloc_b((size_t)N_NODES * 4);
    unsigned short* csr = (unsigned short*)alloc_b((size_t)N_NODES * CAP * 2);     // 6.4 MB
    unsigned short* W1p = (unsigned short*)alloc_b((size_t)IN_CH * F1 * 2);        // 64 KB
    unsigned short* W2p = (unsigned short*)alloc_b((size_t)F1 * HID * 2);          // 32 KB

    // 1) zero cnt + pack weights
    init_kernel<<<(N_NODES + 255) / 256, 256, 0, stream>>>(cnt, W1, W1p, W2, W2p);

    // 2) fixed-cap CSR scatter || gemm1 (+ layer-1 logits)
    scatter_gemm1<<<SCAT_B, 256, 0, stream>>>(ei, cnt, csr, x, (const short*)W1p,
                                              a_src1, a_dst1, H1b, al_s1, al_d1);

    // 3) layer-1 aggregation -> (LDS) -> GEMM2 (+ layer-2 logits)
    agg1_gemm2<<<N_NODES / 16, 256, 0, stream>>>(cnt, csr, al_s1, al_d1,
                                                 (const uint2*)H1b, b1,
                                                 (const short*)W2p, a_src2, a_dst2,
                                                 H2b, al_s2, al_d2);

    // 4) layer-2 aggregation (writes bf16 out2)
    agg2_csr<<<N_NODES / 4, 256, 0, stream>>>(cnt, csr, al_s2, al_d2,
                                              (const uint2*)H2b, (uint2*)out2b);

    // 5) readout (4 waves/graph, bf16 input)
    pool_fc_kernel<<<NUM_GRAPHS, 256, 0, stream>>>(out2b, b2, batch, fc_w, fc_b, out);
}